// Round 1
// baseline (583.255 us; speedup 1.0000x reference)
//
#include <hip/hip_runtime.h>
#include <hip/hip_bf16.h>
#include <math.h>

#define NTOK 1024
#define DDIM 768
#define MDIM 3072
#define GN 4
#define EN 8
#define NEXP 32
#define NPAIR 8192
#define EPSW 1e-6f

typedef __attribute__((ext_vector_type(4))) float f32x4;
typedef __attribute__((ext_vector_type(4))) int   i32x4;
typedef __attribute__((ext_vector_type(4))) unsigned short u16x4;
typedef __attribute__((ext_vector_type(8))) __bf16 bf16x8;

__device__ __forceinline__ unsigned short f2bf(float f) {
  unsigned u = __builtin_bit_cast(unsigned, f);
  u += 0x7FFFu + ((u >> 16) & 1u);
  return (unsigned short)(u >> 16);
}

// ---------------------------------------------------------------------------
// Kernel 1: gating. One block per token. Computes 4 group logits + 32 expert
// logits in fp32, top-2 groups / top-4 experts (stable argmax = jax.lax.top_k
// tiebreak), softmax over selected, EPS zeroing, emits 8 (expert, weight)
// pairs per token and histograms counts.
// ---------------------------------------------------------------------------
__global__ __launch_bounds__(256) void gating_kernel(
    const float* __restrict__ x, const float* __restrict__ Wg,
    const float* __restrict__ bg, const float* __restrict__ We,
    const float* __restrict__ be, int* __restrict__ counts,
    int* __restrict__ pair_e, float* __restrict__ pair_w)
{
  __shared__ float xr[DDIM];
  __shared__ float logits[36];
  const int n = blockIdx.x;
  const int tid = threadIdx.x;
  const float* xp = x + (size_t)n * DDIM;
  for (int d = tid; d < DDIM; d += 256) xr[d] = xp[d];
  __syncthreads();

  const int w = tid >> 6, lane = tid & 63;
  for (int j = 0; j < 9; ++j) {
    const int o = w + 4 * j;  // 0..35
    float s = 0.f;
    if (o < 4) {
      for (int d = lane; d < DDIM; d += 64) s += xr[d] * Wg[d * GN + o];
    } else {
      const int g = (o - 4) >> 3, e = (o - 4) & 7;
      const float* wp = We + (size_t)g * DDIM * EN + e;
      for (int d = lane; d < DDIM; d += 64) s += xr[d] * wp[d * EN];
    }
    for (int off = 32; off; off >>= 1) s += __shfl_xor(s, off);
    if (lane == 0) logits[o] = s + ((o < 4) ? bg[o] : be[o - 4]);
  }
  __syncthreads();

  if (tid == 0) {
    float gl[4];
    for (int i = 0; i < 4; ++i) gl[i] = logits[i];
    // top-2 groups (first-max wins ties, like stable top_k)
    int i0 = 0;
    for (int i = 1; i < 4; ++i) if (gl[i] > gl[i0]) i0 = i;
    int i1 = -1;
    for (int i = 0; i < 4; ++i) {
      if (i == i0) continue;
      if (i1 < 0 || gl[i] > gl[i1]) i1 = i;
    }
    const float m = gl[i0];
    const float e1 = expf(gl[i1] - m);
    const float s2 = 1.f + e1;
    float gv[2] = { 1.f / s2, e1 / s2 };
    int gi[2] = { i0, i1 };
    for (int r = 0; r < 2; ++r) if (gv[r] < EPSW) gv[r] = 0.f;

    for (int r = 0; r < 2; ++r) {
      const int g = gi[r];
      float el[8];
      for (int e = 0; e < 8; ++e) el[e] = logits[4 + g * 8 + e];
      int sel[4];
      for (int q = 0; q < 4; ++q) {
        int best = -1;
        for (int e = 0; e < 8; ++e) {
          bool used = false;
          for (int p = 0; p < q; ++p) if (sel[p] == e) used = true;
          if (used) continue;
          if (best < 0 || el[e] > el[best]) best = e;
        }
        sel[q] = best;
      }
      const float mm = el[sel[0]];
      float ex[4]; float ss = 0.f;
      for (int q = 0; q < 4; ++q) { ex[q] = expf(el[sel[q]] - mm); ss += ex[q]; }
      for (int q = 0; q < 4; ++q) {
        float ew = ex[q] / ss;
        if (ew < EPSW) ew = 0.f;
        const int gbl = g * 8 + sel[q];
        const int j = r * 4 + q;
        pair_e[n * 8 + j] = gbl;
        pair_w[n * 8 + j] = gv[r] * ew;
        atomicAdd(&counts[gbl], 1);
      }
    }
  }
}

// ---------------------------------------------------------------------------
// Kernel 2: exclusive scan of 32 counts (tiny, serial).
// ---------------------------------------------------------------------------
__global__ void scan_kernel(const int* __restrict__ counts, int* __restrict__ offsets)
{
  if (threadIdx.x == 0) {
    int a = 0;
    for (int i = 0; i < NEXP; ++i) { offsets[i] = a; a += counts[i]; }
  }
}

// ---------------------------------------------------------------------------
// Kernel 3: scatter tokens to expert segments; gather x rows as bf16.
// ---------------------------------------------------------------------------
__global__ __launch_bounds__(256) void scatter_kernel(
    const float* __restrict__ x, const int* __restrict__ pair_e,
    const float* __restrict__ pair_w, const int* __restrict__ offsets,
    int* __restrict__ cursor, int* __restrict__ token_slots,
    float* __restrict__ slot_w, unsigned short* __restrict__ Xg)
{
  __shared__ int slots[8];
  const int n = blockIdx.x, tid = threadIdx.x;
  if (tid < 8) {
    const int e = pair_e[n * 8 + tid];
    const int s = offsets[e] + atomicAdd(&cursor[e], 1);
    slots[tid] = s;
    token_slots[n * 8 + tid] = s;
    slot_w[s] = pair_w[n * 8 + tid];
  }
  __syncthreads();
  const float* xp = x + (size_t)n * DDIM;
  for (int d = tid; d < DDIM; d += 256) {
    const unsigned short h = f2bf(xp[d]);
#pragma unroll
    for (int j = 0; j < 8; ++j) Xg[(size_t)slots[j] * DDIM + d] = h;
  }
}

// ---------------------------------------------------------------------------
// GEMM: C[rows x NLD] = A_seg[rows x K](bf16) * B[ge][K x NLD](fp32) per
// expert segment. 128x128 tile, BK=32, 4 waves, mfma 16x16x32 bf16.
// A staged as bf16 16B chunks (XOR-swizzled); B register-staged with
// transpose + fp32->bf16 convert into Bt[n][k] (XOR-swizzled).
// EPI 0: H = bf16(gelu(C + b1));  EPI 1: O = slot_w * (C + b2)  (fp32).
// ---------------------------------------------------------------------------
template<int K, int NLD, int EPI>
__global__ __launch_bounds__(256) void moe_gemm(
    const unsigned short* __restrict__ A, const float* __restrict__ B,
    const float* __restrict__ bias, const int* __restrict__ counts,
    const int* __restrict__ offsets, const float* __restrict__ slot_w,
    unsigned short* __restrict__ Hout, float* __restrict__ Oout)
{
  const int ge = blockIdx.z;
  const int cnt = counts[ge];
  const int by = blockIdx.y;
  if (by * 128 >= cnt) return;
  const int off = offsets[ge];
  const int nb = blockIdx.x;

  __shared__ __align__(16) unsigned char ldsA[128 * 64];
  __shared__ __align__(16) unsigned char ldsB[128 * 64];

  const int tid = threadIdx.x;

  // A staging: thread covers (row, chunk) = (tid>>2, tid&3) and row+64.
  const int ar = tid >> 2;
  const int ac = tid & 3;
  int gr0 = by * 128 + ar;       if (gr0 >= cnt) gr0 = cnt - 1;
  int gr1 = by * 128 + ar + 64;  if (gr1 >= cnt) gr1 = cnt - 1;
  const unsigned short* aq0 = A + (size_t)(off + gr0) * K + ac * 8;
  const unsigned short* aq1 = A + (size_t)(off + gr1) * K + ac * 8;
  unsigned char* la0 = ldsA + ar * 64 + ((ac ^ ((ar >> 1) & 3)) * 16);
  unsigned char* la1 = ldsA + (ar + 64) * 64 + ((ac ^ ((ar >> 1) & 3)) * 16);

  // B staging geometry
  const int kq = tid >> 5;  // 0..7 (k-quad)
  const int ln = tid & 31;
  const float* bbase = B + (size_t)ge * K * NLD + (size_t)nb * 128;

  // wave / fragment geometry
  const int w = tid >> 6;
  const int lane = tid & 63;
  const int wr = (w >> 1) * 64;
  const int wc = (w & 1) * 64;
  const int l15 = lane & 15;
  const int l4 = lane >> 4;

  int aoff[4], boff[4];
#pragma unroll
  for (int mf = 0; mf < 4; ++mf) {
    const int r = wr + mf * 16 + l15;
    aoff[mf] = r * 64 + ((l4 ^ ((r >> 1) & 3)) * 16);
  }
#pragma unroll
  for (int nf = 0; nf < 4; ++nf) {
    const int c = wc + nf * 16 + l15;
    boff[nf] = c * 64 + ((l4 ^ ((c >> 1) & 3)) * 16);
  }

  f32x4 acc[4][4];
#pragma unroll
  for (int mf = 0; mf < 4; ++mf)
#pragma unroll
    for (int nf = 0; nf < 4; ++nf)
      acc[mf][nf] = (f32x4){0.f, 0.f, 0.f, 0.f};

  for (int kt = 0; kt < K / 32; ++kt) {
    // stage A (already bf16, K-contig): 2x 16B per thread
    const i32x4 av0 = *(const i32x4*)(aq0 + kt * 32);
    const i32x4 av1 = *(const i32x4*)(aq1 + kt * 32);
    *(i32x4*)la0 = av0;
    *(i32x4*)la1 = av1;
    // stage B: 16 scalar fp32 loads -> transpose -> bf16 -> 4x ds_write_b64
#pragma unroll
    for (int i = 0; i < 4; ++i) {
      const int n = ln + 32 * i;
      const float* bp = bbase + (size_t)(kt * 32 + kq * 4) * NLD + n;
      u16x4 p;
      p.x = f2bf(bp[0]);
      p.y = f2bf(bp[(size_t)NLD]);
      p.z = f2bf(bp[(size_t)2 * NLD]);
      p.w = f2bf(bp[(size_t)3 * NLD]);
      const int bo = n * 64 + (((kq >> 1) ^ ((n >> 1) & 3)) * 16) + ((kq & 1) * 8);
      *(u16x4*)(ldsB + bo) = p;
    }
    __syncthreads();

    bf16x8 afr[4], bfr[4];
#pragma unroll
    for (int mf = 0; mf < 4; ++mf)
      afr[mf] = __builtin_bit_cast(bf16x8, *(const i32x4*)(ldsA + aoff[mf]));
#pragma unroll
    for (int nf = 0; nf < 4; ++nf)
      bfr[nf] = __builtin_bit_cast(bf16x8, *(const i32x4*)(ldsB + boff[nf]));
#pragma unroll
    for (int mf = 0; mf < 4; ++mf)
#pragma unroll
      for (int nf = 0; nf < 4; ++nf)
        acc[mf][nf] = __builtin_amdgcn_mfma_f32_16x16x32_bf16(
            afr[mf], bfr[nf], acc[mf][nf], 0, 0, 0);
    __syncthreads();
  }

  // epilogue. C/D layout: col = lane&15, row = (lane>>4)*4 + j
#pragma unroll
  for (int mf = 0; mf < 4; ++mf) {
    const int rbase = wr + mf * 16 + l4 * 4;
#pragma unroll
    for (int nf = 0; nf < 4; ++nf) {
      const int col = nb * 128 + wc + nf * 16 + l15;
      const float bv = bias[(size_t)ge * NLD + col];
#pragma unroll
      for (int j = 0; j < 4; ++j) {
        const int r = by * 128 + rbase + j;
        if (r < cnt) {
          const int slot = off + r;
          const float v = acc[mf][nf][j] + bv;
          if constexpr (EPI == 0) {
            const float gl = 0.5f * v * (1.f + erff(v * 0.70710678118654752f));
            Hout[(size_t)slot * NLD + col] = f2bf(gl);
          } else {
            Oout[(size_t)slot * NLD + col] = slot_w[slot] * v;
          }
        }
      }
    }
  }
}

// ---------------------------------------------------------------------------
// Kernel 6: per-token gather-sum of its 8 weighted expert outputs.
// ---------------------------------------------------------------------------
__global__ __launch_bounds__(256) void gather_kernel(
    const int* __restrict__ token_slots, const float* __restrict__ O,
    float* __restrict__ y)
{
  const int n = blockIdx.x, tid = threadIdx.x;
  int s[8];
#pragma unroll
  for (int j = 0; j < 8; ++j) s[j] = token_slots[n * 8 + j];
  for (int d = tid; d < DDIM; d += 256) {
    float a = 0.f;
#pragma unroll
    for (int j = 0; j < 8; ++j) a += O[(size_t)s[j] * DDIM + d];
    y[(size_t)n * DDIM + d] = a;
  }
}

// ---------------------------------------------------------------------------
// Workspace layout (bytes):
//   0      counts[32]          256   offsets[32]       512  cursor[32]
//   1024   pair_e[8192] i32    33792 pair_w[8192] f32
//   66560  token_slots[8192]   99328 slot_w[8192] f32
//   132096 Xg[8192][768] bf16  (12.6 MB)
//   12715008 H[8192][3072] bf16 (50.3 MB)
//   63046656 O[8192][768] f32   (25.2 MB)   total ~88.2 MB
// ---------------------------------------------------------------------------
extern "C" void kernel_launch(void* const* d_in, const int* in_sizes, int n_in,
                              void* d_out, int out_size, void* d_ws, size_t ws_size,
                              hipStream_t stream)
{
  const float* x  = (const float*)d_in[0];
  const float* Wg = (const float*)d_in[1];
  const float* bg = (const float*)d_in[2];
  const float* We = (const float*)d_in[3];
  const float* be = (const float*)d_in[4];
  const float* W1 = (const float*)d_in[5];
  const float* b1 = (const float*)d_in[6];
  const float* W2 = (const float*)d_in[7];
  const float* b2 = (const float*)d_in[8];
  float* y = (float*)d_out;

  char* ws = (char*)d_ws;
  int*   counts      = (int*)(ws + 0);
  int*   offsets     = (int*)(ws + 256);
  int*   cursor      = (int*)(ws + 512);
  int*   pair_e      = (int*)(ws + 1024);
  float* pair_w      = (float*)(ws + 33792);
  int*   token_slots = (int*)(ws + 66560);
  float* slot_w      = (float*)(ws + 99328);
  unsigned short* Xg = (unsigned short*)(ws + 132096);
  unsigned short* H  = (unsigned short*)(ws + 12715008);
  float* O           = (float*)(ws + 63046656);

  hipMemsetAsync(ws, 0, 1024, stream);
  gating_kernel<<<NTOK, 256, 0, stream>>>(x, Wg, bg, We, be, counts, pair_e, pair_w);
  scan_kernel<<<1, 64, 0, stream>>>(counts, offsets);
  scatter_kernel<<<NTOK, 256, 0, stream>>>(x, pair_e, pair_w, offsets, cursor,
                                           token_slots, slot_w, Xg);
  moe_gemm<DDIM, MDIM, 0><<<dim3(MDIM / 128, 8, NEXP), 256, 0, stream>>>(
      Xg, W1, b1, counts, offsets, nullptr, H, nullptr);
  moe_gemm<MDIM, DDIM, 1><<<dim3(DDIM / 128, 8, NEXP), 256, 0, stream>>>(
      H, W2, b2, counts, offsets, slot_w, nullptr, O);
  gather_kernel<<<NTOK, 256, 0, stream>>>(token_slots, O, y);
}